// Round 6
// baseline (153.999 us; speedup 1.0000x reference)
//
#include <hip/hip_runtime.h>

#define NB     64            // batch
#define HH     512
#define WW     512
#define HWSZ   (HH * WW)     // 262144 floats per batch image
#define NPTS   512
#define RBPB   8             // reduce blocks per batch
#define NRB    (NB * RBPB)   // 512 reduce-role blocks
#define NBLK   (NB + NRB)    // 576 total blocks

__device__ __forceinline__ float waveReduceSum(float v) {
    for (int o = 32; o > 0; o >>= 1) v += __shfl_down(v, o);
    return v;
}

// Grid = 576 blocks x 512 threads. LDS ~4.4 KB (no occupancy cap).
//  blocks [0, NB)     : scatter role — per-batch TS/T2/DOT, NO hash:
//                       TS, DOT are dedup-free sums; T2 via pairwise overlap
//                       (5x5 interior table + explicit fallback at borders).
//  blocks [NB, NBLK)  : reduce role — 8-deep ILP streaming of pred chunks.
__global__ __launch_bounds__(512)
void k_main(const float* __restrict__ pred, const float* __restrict__ points,
            const int* __restrict__ pHin, const int* __restrict__ pWin,
            float* __restrict__ Spart, float* __restrict__ P2part,
            float* __restrict__ T2, float* __restrict__ DOT, float* __restrict__ TS) {
    __shared__ int   xs[NPTS], ys[NPTS];
    __shared__ float T5[25];          // interior pair-overlap table, index (dY+2)*5+(dX+2)
    __shared__ float red[24];         // block-reduce scratch
    const int tid = threadIdx.x;

    if (blockIdx.x >= NB) {
        // ---------------- reduce role ----------------
        const int rb = blockIdx.x - NB;                        // 0..511
        const float4* base = (const float4*)pred + (size_t)rb * (HWSZ / RBPB / 4);
        float s = 0.f, q = 0.f;
#pragma unroll
        for (int it = 0; it < 2; ++it) {
            float4 v0 = base[tid + (it * 8 + 0) * 512];
            float4 v1 = base[tid + (it * 8 + 1) * 512];
            float4 v2 = base[tid + (it * 8 + 2) * 512];
            float4 v3 = base[tid + (it * 8 + 3) * 512];
            float4 v4 = base[tid + (it * 8 + 4) * 512];
            float4 v5 = base[tid + (it * 8 + 5) * 512];
            float4 v6 = base[tid + (it * 8 + 6) * 512];
            float4 v7 = base[tid + (it * 8 + 7) * 512];
            s += (v0.x + v0.y) + (v0.z + v0.w);  q += v0.x*v0.x + v0.y*v0.y + v0.z*v0.z + v0.w*v0.w;
            s += (v1.x + v1.y) + (v1.z + v1.w);  q += v1.x*v1.x + v1.y*v1.y + v1.z*v1.z + v1.w*v1.w;
            s += (v2.x + v2.y) + (v2.z + v2.w);  q += v2.x*v2.x + v2.y*v2.y + v2.z*v2.z + v2.w*v2.w;
            s += (v3.x + v3.y) + (v3.z + v3.w);  q += v3.x*v3.x + v3.y*v3.y + v3.z*v3.z + v3.w*v3.w;
            s += (v4.x + v4.y) + (v4.z + v4.w);  q += v4.x*v4.x + v4.y*v4.y + v4.z*v4.z + v4.w*v4.w;
            s += (v5.x + v5.y) + (v5.z + v5.w);  q += v5.x*v5.x + v5.y*v5.y + v5.z*v5.z + v5.w*v5.w;
            s += (v6.x + v6.y) + (v6.z + v6.w);  q += v6.x*v6.x + v6.y*v6.y + v6.z*v6.z + v6.w*v6.w;
            s += (v7.x + v7.y) + (v7.z + v7.w);  q += v7.x*v7.x + v7.y*v7.y + v7.z*v7.z + v7.w*v7.w;
        }
        s = waveReduceSum(s);
        q = waveReduceSum(q);
        const int wave = tid >> 6, lane = tid & 63;
        if (lane == 0) { red[wave] = s; red[8 + wave] = q; }
        __syncthreads();
        if (tid == 0) {
            float a = 0.f, b2 = 0.f;
            for (int w = 0; w < 8; ++w) { a += red[w]; b2 += red[8 + w]; }
            Spart[rb] = a; P2part[rb] = b2;
        }
        return;
    }

    // ---------------- scatter role ----------------
    const int b = blockIdx.x;
    const float scale_w = (float)WW / (float)(*pWin);
    const float scale_h = (float)HH / (float)(*pHin);
    const float wE = expf(-0.5f);
    const float wD = expf(-0.70710678118654752440f);           // exp(-sqrt(2)/2)

    // Build interior overlap table: T5[(dY+2)*5+(dX+2)] = sum over stamp cells
    // shared by two interior points at offset (dX,dY).
    if (tid < 25) {
        int dY = tid / 5 - 2, dX = tid % 5 - 2;
        float acc = 0.f;
        for (int dyi = -1; dyi <= 1; ++dyi)
            for (int dxi = -1; dxi <= 1; ++dxi) {
                int dyj = dyi - dY, dxj = dxi - dX;
                if (dyj < -1 || dyj > 1 || dxj < -1 || dxj > 1) continue;
                int d2i = dyi * dyi + dxi * dxi;
                int d2j = dyj * dyj + dxj * dxj;
                float wi = (d2i == 0) ? 1.f : ((d2i == 1) ? wE : wD);
                float wj = (d2j == 0) ? 1.f : ((d2j == 1) ? wE : wD);
                acc += wi * wj;
            }
        T5[tid] = acc;
    }

    // One point per thread.
    const float2 pt = ((const float2*)points)[(size_t)b * NPTS + tid];
    const int xi = (int)fminf(fmaxf(pt.x * scale_w, 0.f), (float)(WW - 1));
    const int yi = (int)fminf(fmaxf(pt.y * scale_h, 0.f), (float)(HH - 1));
    xs[tid] = xi; ys[tid] = yi;

    // wsum + dot: duplicates are correct here (linear in t).
    const float* pb = pred + (size_t)b * HWSZ;
    float wsum = 0.f, dot = 0.f;
#pragma unroll
    for (int dy = -1; dy <= 1; ++dy)
#pragma unroll
        for (int dx = -1; dx <= 1; ++dx) {
            int ny = yi + dy, nx = xi + dx;
            if (ny < 0 || ny >= HH || nx < 0 || nx >= WW) continue;
            int d2 = dy * dy + dx * dx;
            float w = (d2 == 0) ? 1.f : ((d2 == 1) ? wE : wD);
            wsum += w;
            dot  += w * pb[ny * WW + nx];
        }
    __syncthreads();   // xs/ys/T5 ready

    // t2 = sum over all pairs (incl. self) of stamp overlap.
    const bool ii = (xi >= 1) & (xi <= WW - 2) & (yi >= 1) & (yi <= HH - 2);
    float t2 = 0.f;
    for (int j = 0; j < NPTS; ++j) {
        int xj = xs[j], yj = ys[j];
        int dX = xj - xi, dY = yj - yi;
        if ((unsigned)(dX + 2) > 4u || (unsigned)(dY + 2) > 4u) continue;
        bool ij = (xj >= 1) & (xj <= WW - 2) & (yj >= 1) & (yj <= HH - 2);
        if (ii & ij) {
            t2 += T5[(dY + 2) * 5 + (dX + 2)];
        } else {
            // explicit overlap with boundary clipping
            for (int dyi = -1; dyi <= 1; ++dyi)
                for (int dxi = -1; dxi <= 1; ++dxi) {
                    int cy = yi + dyi, cx = xi + dxi;
                    if (cy < 0 || cy >= HH || cx < 0 || cx >= WW) continue;
                    int dyj = dyi - dY, dxj = dxi - dX;
                    if (dyj < -1 || dyj > 1 || dxj < -1 || dxj > 1) continue;
                    int d2i = dyi * dyi + dxi * dxi;
                    int d2j = dyj * dyj + dxj * dxj;
                    float wi = (d2i == 0) ? 1.f : ((d2i == 1) ? wE : wD);
                    float wj = (d2j == 0) ? 1.f : ((d2j == 1) ? wE : wD);
                    t2 += wi * wj;
                }
        }
    }

    wsum = waveReduceSum(wsum);
    t2   = waveReduceSum(t2);
    dot  = waveReduceSum(dot);
    const int wave = tid >> 6, lane = tid & 63;
    if (lane == 0) { red[wave] = wsum; red[8 + wave] = t2; red[16 + wave] = dot; }
    __syncthreads();
    if (tid == 0) {
        float a0 = 0.f, a1 = 0.f, a2 = 0.f;
        for (int w = 0; w < 8; ++w) { a0 += red[w]; a1 += red[8 + w]; a2 += red[16 + w]; }
        TS[b] = a0; T2[b] = a1; DOT[b] = a2;
    }
}

// Finalize: one wave, f64.
__global__ __launch_bounds__(64)
void k_fin(const float* __restrict__ Spart, const float* __restrict__ P2part,
           const float* __restrict__ T2, const float* __restrict__ DOT,
           const float* __restrict__ TS, const int* __restrict__ pCell,
           float* __restrict__ out) {
    const int t = threadIdx.x;
    double cl = 0.0, sl = 0.0;
    if (t < NB) {
        double s = 0.0, p2 = 0.0;
#pragma unroll
        for (int c = 0; c < RBPB; ++c) {
            s  += (double)Spart[t * RBPB + c];
            p2 += (double)P2part[t * RBPB + c];
        }
        cl = fabs(s / (double)(*pCell) - (double)NPTS);
        double sn = s + 1e-8;
        double ts = (double)TS[t];
        double term = p2 / (sn * sn)
                    - 2.0 * (double)DOT[t] / (sn * ts)
                    + (double)T2[t] / (ts * ts);
        sl = term / (double)HWSZ;
    }
    for (int o = 32; o > 0; o >>= 1) { cl += __shfl_down(cl, o); sl += __shfl_down(sl, o); }
    if (t == 0) {
        double count_loss   = cl / (double)NB;
        double spatial_loss = sl / (double)NB;
        double total = 2.5 * count_loss + 0.1 * spatial_loss;   // scale_loss == 0
        out[0] = (float)total;
        out[1] = (float)count_loss;
        out[2] = (float)spatial_loss;
    }
}

extern "C" void kernel_launch(void* const* d_in, const int* in_sizes, int n_in,
                              void* d_out, int out_size, void* d_ws, size_t ws_size,
                              hipStream_t stream) {
    const float* pred   = (const float*)d_in[0];
    const float* points = (const float*)d_in[1];
    const int*   cell   = (const int*)d_in[2];
    const int*   hin    = (const int*)d_in[3];
    const int*   win    = (const int*)d_in[4];
    float* out = (float*)d_out;

    float* Spart  = (float*)d_ws;        // NRB floats (written unconditionally)
    float* P2part = Spart + NRB;         // NRB floats
    float* T2     = Spart + 2 * NRB;     // NB floats
    float* DOT    = T2 + NB;             // NB floats
    float* TS     = DOT + NB;            // NB floats

    k_main<<<NBLK, 512, 0, stream>>>(pred, points, hin, win,
                                     Spart, P2part, T2, DOT, TS);
    k_fin<<<1, 64, 0, stream>>>(Spart, P2part, T2, DOT, TS, cell, out);
}

// Round 7
// 119.394 us; speedup vs baseline: 1.2898x; 1.2898x over previous
//
#include <hip/hip_runtime.h>

#define NB     64            // batch
#define HH     512
#define WW     512
#define HWSZ   (HH * WW)     // 262144 floats per batch image
#define NPTS   512
#define CPB    32            // reduce chunks per batch
#define NRB    (NB * CPB)    // 2048 reduce blocks
#define JBLK   4             // j-range blocks per batch in scatter
#define NSB    (NB * JBLK)   // 256 scatter blocks
#define C4     (HWSZ / CPB / 4)   // float4 per reduce chunk = 2048

// ---------------- K1: streaming reduce (sum, sum^2 of pred) ----------------
// 2048 blocks x 256 threads; each block: one contiguous 8 KB-float4 chunk of
// one batch. 8 independent float4 loads per thread, fully unrolled.
// Partials chunk-major: Spart[c*64 + b] for coalesced k_fin reads.
__global__ __launch_bounds__(256)
void k_reduce(const float* __restrict__ pred,
              float* __restrict__ Spart, float* __restrict__ P2part) {
    const int b = blockIdx.x >> 5;          // / CPB
    const int c = blockIdx.x & (CPB - 1);
    const float4* __restrict__ base =
        (const float4*)pred + (size_t)b * (HWSZ / 4) + (size_t)c * C4;
    const int tid = threadIdx.x;

    float4 v0 = base[tid + 0 * 256];
    float4 v1 = base[tid + 1 * 256];
    float4 v2 = base[tid + 2 * 256];
    float4 v3 = base[tid + 3 * 256];
    float4 v4 = base[tid + 4 * 256];
    float4 v5 = base[tid + 5 * 256];
    float4 v6 = base[tid + 6 * 256];
    float4 v7 = base[tid + 7 * 256];

    float s = 0.f, q = 0.f;
    s += (v0.x + v0.y) + (v0.z + v0.w);  q += v0.x*v0.x + v0.y*v0.y + v0.z*v0.z + v0.w*v0.w;
    s += (v1.x + v1.y) + (v1.z + v1.w);  q += v1.x*v1.x + v1.y*v1.y + v1.z*v1.z + v1.w*v1.w;
    s += (v2.x + v2.y) + (v2.z + v2.w);  q += v2.x*v2.x + v2.y*v2.y + v2.z*v2.z + v2.w*v2.w;
    s += (v3.x + v3.y) + (v3.z + v3.w);  q += v3.x*v3.x + v3.y*v3.y + v3.z*v3.z + v3.w*v3.w;
    s += (v4.x + v4.y) + (v4.z + v4.w);  q += v4.x*v4.x + v4.y*v4.y + v4.z*v4.z + v4.w*v4.w;
    s += (v5.x + v5.y) + (v5.z + v5.w);  q += v5.x*v5.x + v5.y*v5.y + v5.z*v5.z + v5.w*v5.w;
    s += (v6.x + v6.y) + (v6.z + v6.w);  q += v6.x*v6.x + v6.y*v6.y + v6.z*v6.z + v6.w*v6.w;
    s += (v7.x + v7.y) + (v7.z + v7.w);  q += v7.x*v7.x + v7.y*v7.y + v7.z*v7.z + v7.w*v7.w;

    for (int o = 32; o > 0; o >>= 1) { s += __shfl_down(s, o); q += __shfl_down(q, o); }
    __shared__ float red[8];
    const int wave = tid >> 6, lane = tid & 63;
    if (lane == 0) { red[wave] = s; red[4 + wave] = q; }
    __syncthreads();
    if (tid == 0) {
        float a  = (red[0] + red[1]) + (red[2] + red[3]);
        float b2 = (red[4] + red[5]) + (red[6] + red[7]);
        Spart[c * NB + b]  = a;
        P2part[c * NB + b] = b2;
    }
}

// ---------------- K2: scatter terms (TS, DOT, T2) — no dense target --------
// TS and DOT are linear in t (duplicates fine). T2 = sum over point pairs of
// stamp overlap: 5x5 interior table; explicit clipped fallback at borders.
// Grid = NB*JBLK blocks x 512 threads. Block (b, jb): all 512 keys in LDS,
// thread i processes j in [jb*128, (jb+1)*128) reading packed keys as uint4.
__global__ __launch_bounds__(512)
void k_scatter(const float* __restrict__ pred, const float* __restrict__ points,
               const int* __restrict__ pHin, const int* __restrict__ pWin,
               float* __restrict__ T2part, float* __restrict__ DOT,
               float* __restrict__ TS) {
    __shared__ __align__(16) unsigned keys[NPTS];
    __shared__ float T5[25];
    __shared__ float red[24];
    const int tid = threadIdx.x;
    const int b  = blockIdx.x >> 2;         // / JBLK
    const int jb = blockIdx.x & (JBLK - 1);

    const float scale_w = (float)WW / (float)(*pWin);
    const float scale_h = (float)HH / (float)(*pHin);
    const float wE = expf(-0.5f);
    const float wD = expf(-0.70710678118654752440f);   // exp(-sqrt(2)/2)

    if (tid < 25) {
        int dY = tid / 5 - 2, dX = tid % 5 - 2;
        float acc = 0.f;
        for (int dyi = -1; dyi <= 1; ++dyi)
            for (int dxi = -1; dxi <= 1; ++dxi) {
                int dyj = dyi - dY, dxj = dxi - dX;
                if (dyj < -1 || dyj > 1 || dxj < -1 || dxj > 1) continue;
                int d2i = dyi * dyi + dxi * dxi;
                int d2j = dyj * dyj + dxj * dxj;
                float wi = (d2i == 0) ? 1.f : ((d2i == 1) ? wE : wD);
                float wj = (d2j == 0) ? 1.f : ((d2j == 1) ? wE : wD);
                acc += wi * wj;
            }
        T5[tid] = acc;
    }

    const float2 pt = ((const float2*)points)[(size_t)b * NPTS + tid];
    const int xi = (int)fminf(fmaxf(pt.x * scale_w, 0.f), (float)(WW - 1));
    const int yi = (int)fminf(fmaxf(pt.y * scale_h, 0.f), (float)(HH - 1));
    keys[tid] = ((unsigned)yi << 16) | (unsigned)xi;
    __syncthreads();

    // --- TS & DOT (block jb==0 only; linear in t, duplicates correct) ---
    float wsum = 0.f, dot = 0.f;
    if (jb == 0) {
        const float* pb = pred + (size_t)b * HWSZ;
#pragma unroll
        for (int dy = -1; dy <= 1; ++dy)
#pragma unroll
            for (int dx = -1; dx <= 1; ++dx) {
                int ny = yi + dy, nx = xi + dx;
                if (ny < 0 || ny >= HH || nx < 0 || nx >= WW) continue;
                int d2 = dy * dy + dx * dx;
                float w = (d2 == 0) ? 1.f : ((d2 == 1) ? wE : wD);
                wsum += w;
                dot  += w * pb[ny * WW + nx];
            }
    }

    // --- T2: pairwise overlap over this block's j-range (128 keys) ---
    const bool ii = (xi >= 1) & (xi <= WW - 2) & (yi >= 1) & (yi <= HH - 2);
    float t2 = 0.f;
    const uint4* k4 = (const uint4*)(keys + jb * (NPTS / JBLK));   // 32 uint4
#pragma unroll 4
    for (int j4 = 0; j4 < NPTS / JBLK / 4; ++j4) {
        uint4 kk = k4[j4];
#pragma unroll
        for (int e = 0; e < 4; ++e) {
            unsigned k = (e == 0) ? kk.x : (e == 1) ? kk.y : (e == 2) ? kk.z : kk.w;
            int xj = (int)(k & 0xFFFFu), yj = (int)(k >> 16);
            int dX = xj - xi, dY = yj - yi;
            if ((unsigned)(dX + 2) > 4u || (unsigned)(dY + 2) > 4u) continue;
            bool ij = (xj >= 1) & (xj <= WW - 2) & (yj >= 1) & (yj <= HH - 2);
            if (ii & ij) {
                t2 += T5[(dY + 2) * 5 + (dX + 2)];
            } else {
                for (int dyi = -1; dyi <= 1; ++dyi)
                    for (int dxi = -1; dxi <= 1; ++dxi) {
                        int cy = yi + dyi, cx = xi + dxi;
                        if (cy < 0 || cy >= HH || cx < 0 || cx >= WW) continue;
                        int dyj = dyi - dY, dxj = dxi - dX;
                        if (dyj < -1 || dyj > 1 || dxj < -1 || dxj > 1) continue;
                        int d2i = dyi * dyi + dxi * dxi;
                        int d2j = dyj * dyj + dxj * dxj;
                        float wi = (d2i == 0) ? 1.f : ((d2i == 1) ? wE : wD);
                        float wj = (d2j == 0) ? 1.f : ((d2j == 1) ? wE : wD);
                        t2 += wi * wj;
                    }
            }
        }
    }

    for (int o = 32; o > 0; o >>= 1) {
        wsum += __shfl_down(wsum, o);
        t2   += __shfl_down(t2, o);
        dot  += __shfl_down(dot, o);
    }
    const int wave = tid >> 6, lane = tid & 63;
    if (lane == 0) { red[wave] = wsum; red[8 + wave] = t2; red[16 + wave] = dot; }
    __syncthreads();
    if (tid == 0) {
        float a0 = 0.f, a1 = 0.f, a2 = 0.f;
        for (int w = 0; w < 8; ++w) { a0 += red[w]; a1 += red[8 + w]; a2 += red[16 + w]; }
        T2part[jb * NB + b] = a1;
        if (jb == 0) { TS[b] = a0; DOT[b] = a2; }
    }
}

// ---------------- K3: finalize (one wave, f64) ----------------
__global__ __launch_bounds__(64)
void k_fin(const float* __restrict__ Spart, const float* __restrict__ P2part,
           const float* __restrict__ T2part, const float* __restrict__ DOT,
           const float* __restrict__ TS, const int* __restrict__ pCell,
           float* __restrict__ out) {
    const int t = threadIdx.x;   // == batch index (NB==64)
    double s = 0.0, p2 = 0.0, t2 = 0.0;
#pragma unroll
    for (int c = 0; c < CPB; ++c) {           // coalesced: lane t reads [c*64+t]
        s  += (double)Spart[c * NB + t];
        p2 += (double)P2part[c * NB + t];
    }
#pragma unroll
    for (int c = 0; c < JBLK; ++c) t2 += (double)T2part[c * NB + t];

    double cl = fabs(s / (double)(*pCell) - (double)NPTS);
    double sn = s + 1e-8;
    double ts = (double)TS[t];
    double term = p2 / (sn * sn)
                - 2.0 * (double)DOT[t] / (sn * ts)
                + t2 / (ts * ts);
    double sl = term / (double)HWSZ;

    for (int o = 32; o > 0; o >>= 1) { cl += __shfl_down(cl, o); sl += __shfl_down(sl, o); }
    if (t == 0) {
        double count_loss   = cl / (double)NB;
        double spatial_loss = sl / (double)NB;
        double total = 2.5 * count_loss + 0.1 * spatial_loss;   // scale_loss == 0
        out[0] = (float)total;
        out[1] = (float)count_loss;
        out[2] = (float)spatial_loss;
    }
}

extern "C" void kernel_launch(void* const* d_in, const int* in_sizes, int n_in,
                              void* d_out, int out_size, void* d_ws, size_t ws_size,
                              hipStream_t stream) {
    const float* pred   = (const float*)d_in[0];
    const float* points = (const float*)d_in[1];
    const int*   cell   = (const int*)d_in[2];
    const int*   hin    = (const int*)d_in[3];
    const int*   win    = (const int*)d_in[4];
    float* out = (float*)d_out;

    float* Spart  = (float*)d_ws;          // NRB floats, chunk-major [c*64+b]
    float* P2part = Spart + NRB;           // NRB floats
    float* T2part = Spart + 2 * NRB;       // NSB floats, [jb*64+b]
    float* DOT    = T2part + NSB;          // NB floats
    float* TS     = DOT + NB;              // NB floats

    k_reduce <<<NRB, 256, 0, stream>>>(pred, Spart, P2part);
    k_scatter<<<NSB, 512, 0, stream>>>(pred, points, hin, win, T2part, DOT, TS);
    k_fin    <<<1,   64,  0, stream>>>(Spart, P2part, T2part, DOT, TS, cell, out);
}